// Round 3
// baseline (51.096 us; speedup 1.0000x reference)
//
#include <hip/hip_runtime.h>
#include <math.h>

#define NN 16
#define GG 4096
#define GP 2              // grid points per block
#define STR 68            // LDS row stride (floats): 16B-aligned rows, item base banks spread
#define NWG (GG / GP)     // 2048 blocks

// compile-time memory fence: stops compiler reordering LDS ops across it.
// HW executes a wave's DS ops in program order, so within-wave overlay
// (read old -> write new, same buffer) is safe with this alone.
#define FENCE() asm volatile("" ::: "memory")

// In-place f32 Gauss-Jordan inverse (no pivoting; matrices are I+eps or SPD).
// Returns log|det| via single log of pivot product (|prod| in [~1e-2, ~7e4]).
__device__ __forceinline__ float gj_inv8(float M[8][8]) {
    float pp = 1.0f;
#pragma unroll
    for (int k = 0; k < 8; ++k) {
        float p = M[k][k];
        pp *= p;
        float ip = 1.0f / p;
        M[k][k] = 1.0f;
#pragma unroll
        for (int jj = 0; jj < 8; ++jj) M[k][jj] *= ip;
#pragma unroll
        for (int ii = 0; ii < 8; ++ii) {
            if (ii == k) continue;
            float d = M[ii][k];
            M[ii][k] = 0.0f;
#pragma unroll
            for (int jj = 0; jj < 8; ++jj) M[ii][jj] = fmaf(-M[k][jj], d, M[ii][jj]);
        }
    }
    return logf(fabsf(pp));
}

// Determinant-only LU (no pivoting). Returns log|det|.
__device__ __forceinline__ float lu_logdet8(float M[8][8]) {
    float pp = 1.0f;
#pragma unroll
    for (int k = 0; k < 8; ++k) {
        float p = M[k][k];
        pp *= p;
        float ip = 1.0f / p;
#pragma unroll
        for (int ii = k + 1; ii < 8; ++ii) {
            float f = M[ii][k] * ip;
#pragma unroll
            for (int jj = k + 1; jj < 8; ++jj) M[ii][jj] = fmaf(-f, M[k][jj], M[ii][jj]);
        }
    }
    return logf(fabsf(pp));
}

__global__ __launch_bounds__(256, 4) void pairkl_kernel(
    const float* __restrict__ omega, const float* __restrict__ links,
    const float* __restrict__ mu, const float* __restrict__ sigma,
    float* __restrict__ out) {
    __shared__ __align__(16) float sh_om[GP][NN][STR];  // omega -> Q
    __shared__ __align__(16) float sh_sg[GP][NN][STR];  // sigma_q
    __shared__ __align__(16) float sh_wv[GP][NN][STR];  // V -> T -> Winv
    __shared__ __align__(16) float sh_si[GP][NN][STR];  // sigma^{-1} -> P
    __shared__ float sh_mu[GP][NN][9];
    __shared__ float sh_u [GP][NN][9];                  // u_i = Winv mu
    __shared__ float sh_w [GP][NN][9];                  // w_j = om^T si mu
    __shared__ float sh_sc[GP][NN][4];                  // ldT,ld1,ldo -> a_i,s_j
#define sh_P sh_si
#define sh_Q sh_om

    const int bid  = blockIdx.x;
    const int work = (bid & 7) * (NWG / 8) + (bid >> 3);  // XCD-bijective swizzle
    const int g0   = work * GP;
    const int t    = threadIdx.x;

    // ---- Phase 0: float4 staging (V = l0+l1-I goes straight into wv) ----
    {
        const float4* om4 = (const float4*)omega;
        const float4* sg4 = (const float4*)sigma;
        const float4* lk4 = (const float4*)links;
        for (int idx = t; idx < GP * NN * 16; idx += 256) {
            int q = idx & 15, i = (idx >> 4) & 15, gl = idx >> 8;
            int g = g0 + gl;
            int b4 = (i * GG + g) * 16 + q;
            float4 o  = om4[b4];
            float4 s  = sg4[b4];
            float4 l0 = lk4[((i * 2 + 0) * GG + g) * 16 + q];
            float4 l1 = lk4[((i * 2 + 1) * GG + g) * 16 + q];
            float4 v  = make_float4(l0.x + l1.x, l0.y + l1.y, l0.z + l1.z, l0.w + l1.w);
            int e0 = q * 4;
            if (((e0 + 0) >> 3) == ((e0 + 0) & 7)) v.x -= 1.f;
            if (((e0 + 1) >> 3) == ((e0 + 1) & 7)) v.y -= 1.f;
            if (((e0 + 2) >> 3) == ((e0 + 2) & 7)) v.z -= 1.f;
            if (((e0 + 3) >> 3) == ((e0 + 3) & 7)) v.w -= 1.f;
            *(float4*)&sh_om[gl][i][e0] = o;
            *(float4*)&sh_sg[gl][i][e0] = s;
            *(float4*)&sh_wv[gl][i][e0] = v;
        }
        {
            int c = t & 7, i = (t >> 3) & 15, gl = t >> 7;  // t<256 == GP*NN*8
            sh_mu[gl][i][c] = mu[(i * GG + g0 + gl) * 8 + c];
        }
    }
    __syncthreads();

    // ---- Phase 1pre: T = omega @ V, row-parallel, all 256 threads ----
    {
        const int item = t >> 3, r = t & 7;
        const int gl = item >> 4, i = item & 15;
        const float* om = &sh_om[gl][i][0];
        const float* vv = &sh_wv[gl][i][0];
        float orow[8];
        *(float4*)&orow[0] = *(const float4*)&om[r * 8];
        *(float4*)&orow[4] = *(const float4*)&om[r * 8 + 4];
        float T[8] = {0, 0, 0, 0, 0, 0, 0, 0};
#pragma unroll
        for (int b = 0; b < 8; ++b) {
            const float4 v0 = *(const float4*)&vv[b * 8];
            const float4 v1 = *(const float4*)&vv[b * 8 + 4];
            float ob = orow[b];
            T[0] = fmaf(ob, v0.x, T[0]); T[1] = fmaf(ob, v0.y, T[1]);
            T[2] = fmaf(ob, v0.z, T[2]); T[3] = fmaf(ob, v0.w, T[3]);
            T[4] = fmaf(ob, v1.x, T[4]); T[5] = fmaf(ob, v1.y, T[5]);
            T[6] = fmaf(ob, v1.z, T[6]); T[7] = fmaf(ob, v1.w, T[7]);
        }
        FENCE();  // all V reads (whole group, same wave) precede T writes
        *(float4*)&sh_wv[gl][i][r * 8]     = make_float4(T[0], T[1], T[2], T[3]);
        *(float4*)&sh_wv[gl][i][r * 8 + 4] = make_float4(T[4], T[5], T[6], T[7]);
    }
    __syncthreads();

    // ---- Phase 1inv: 3 tasks on 3 different waves ----
    if (t < 32) {                       // wave 0: Winv = T^{-1}, ldT
        const int gl = t >> 4, i = t & 15;
        float M[8][8];
#pragma unroll
        for (int a = 0; a < 8; ++a) {
            *(float4*)&M[a][0] = *(const float4*)&sh_wv[gl][i][a * 8];
            *(float4*)&M[a][4] = *(const float4*)&sh_wv[gl][i][a * 8 + 4];
        }
        float ld = gj_inv8(M);
#pragma unroll
        for (int a = 0; a < 8; ++a) {
            *(float4*)&sh_wv[gl][i][a * 8]     = *(const float4*)&M[a][0];
            *(float4*)&sh_wv[gl][i][a * 8 + 4] = *(const float4*)&M[a][4];
        }
        sh_sc[gl][i][0] = ld;
    } else if (t >= 64 && t < 96) {     // wave 1: si = sigma^{-1}, ld1
        const int m = t - 64, gl = m >> 4, i = m & 15;
        float M[8][8];
#pragma unroll
        for (int a = 0; a < 8; ++a) {
            *(float4*)&M[a][0] = *(const float4*)&sh_sg[gl][i][a * 8];
            *(float4*)&M[a][4] = *(const float4*)&sh_sg[gl][i][a * 8 + 4];
        }
        float ld = gj_inv8(M);
#pragma unroll
        for (int a = 0; a < 8; ++a) {
            *(float4*)&sh_si[gl][i][a * 8]     = *(const float4*)&M[a][0];
            *(float4*)&sh_si[gl][i][a * 8 + 4] = *(const float4*)&M[a][4];
        }
        sh_sc[gl][i][1] = ld;
    } else if (t >= 128 && t < 160) {   // wave 2: logdet omega
        const int m = t - 128, gl = m >> 4, i = m & 15;
        float M[8][8];
#pragma unroll
        for (int a = 0; a < 8; ++a) {
            *(float4*)&M[a][0] = *(const float4*)&sh_om[gl][i][a * 8];
            *(float4*)&M[a][4] = *(const float4*)&sh_om[gl][i][a * 8 + 4];
        }
        sh_sc[gl][i][2] = lu_logdet8(M);
    }
    __syncthreads();

    // ---- Phase 1b: P, Q, u, w, scalars. 8 thr/item, no internal barriers ----
    {
        const int item = t >> 3, r = t & 7;
        const int gl = item >> 4, i = item & 15;
        const float* om = &sh_om[gl][i][0];
        const float* si = &sh_si[gl][i][0];
        const float* wv = &sh_wv[gl][i][0];
        float mq[8];
#pragma unroll
        for (int b = 0; b < 8; ++b) mq[b] = sh_mu[gl][i][b];

        // t1 = row r of (om^T si)
        float t1[8] = {0, 0, 0, 0, 0, 0, 0, 0};
#pragma unroll
        for (int a = 0; a < 8; ++a) {
            float oar = om[a * 8 + r];
            const float4 s0 = *(const float4*)&si[a * 8];
            const float4 s1 = *(const float4*)&si[a * 8 + 4];
            t1[0] = fmaf(oar, s0.x, t1[0]); t1[1] = fmaf(oar, s0.y, t1[1]);
            t1[2] = fmaf(oar, s0.z, t1[2]); t1[3] = fmaf(oar, s0.w, t1[3]);
            t1[4] = fmaf(oar, s1.x, t1[4]); t1[5] = fmaf(oar, s1.y, t1[5]);
            t1[6] = fmaf(oar, s1.z, t1[6]); t1[7] = fmaf(oar, s1.w, t1[7]);
        }
        // prow = t1 @ om
        float pr[8] = {0, 0, 0, 0, 0, 0, 0, 0};
#pragma unroll
        for (int b = 0; b < 8; ++b) {
            float tb = t1[b];
            const float4 o0 = *(const float4*)&om[b * 8];
            const float4 o1 = *(const float4*)&om[b * 8 + 4];
            pr[0] = fmaf(tb, o0.x, pr[0]); pr[1] = fmaf(tb, o0.y, pr[1]);
            pr[2] = fmaf(tb, o0.z, pr[2]); pr[3] = fmaf(tb, o0.w, pr[3]);
            pr[4] = fmaf(tb, o1.x, pr[4]); pr[5] = fmaf(tb, o1.y, pr[5]);
            pr[6] = fmaf(tb, o1.z, pr[6]); pr[7] = fmaf(tb, o1.w, pr[7]);
        }
        // u row, w row
        const float4 wr0 = *(const float4*)&wv[r * 8];
        const float4 wr1 = *(const float4*)&wv[r * 8 + 4];
        float uu = wr0.x * mq[0];
        uu = fmaf(wr0.y, mq[1], uu); uu = fmaf(wr0.z, mq[2], uu);
        uu = fmaf(wr0.w, mq[3], uu); uu = fmaf(wr1.x, mq[4], uu);
        uu = fmaf(wr1.y, mq[5], uu); uu = fmaf(wr1.z, mq[6], uu);
        uu = fmaf(wr1.w, mq[7], uu);
        float ww = 0.f;
#pragma unroll
        for (int b = 0; b < 8; ++b) ww = fmaf(t1[b], mq[b], ww);

        float a_i = 0.f, s_i = 0.f;
        if (r == 0) {
            float cc = 0.f;
#pragma unroll
            for (int a = 0; a < 8; ++a) {
                float s = 0.f;
#pragma unroll
                for (int b = 0; b < 8; ++b) s = fmaf(si[a * 8 + b], mq[b], s);
                cc = fmaf(mq[a], s, cc);
            }
            float ldT = sh_sc[gl][i][0], ld1 = sh_sc[gl][i][1], ldo = sh_sc[gl][i][2];
            a_i = 2.f * ldT - ld1;
            s_i = ld1 - 2.f * ldo + cc - 8.0f;
        }
        // Q = wv sg wv^T (reads wv, sg only)
        float t2[8] = {0, 0, 0, 0, 0, 0, 0, 0};
        {
            float wrow[8];
            *(float4*)&wrow[0] = wr0; *(float4*)&wrow[4] = wr1;
#pragma unroll
            for (int b = 0; b < 8; ++b) {
                float wb = wrow[b];
                const float4 g0_ = *(const float4*)&sh_sg[gl][i][b * 8];
                const float4 g1_ = *(const float4*)&sh_sg[gl][i][b * 8 + 4];
                t2[0] = fmaf(wb, g0_.x, t2[0]); t2[1] = fmaf(wb, g0_.y, t2[1]);
                t2[2] = fmaf(wb, g0_.z, t2[2]); t2[3] = fmaf(wb, g0_.w, t2[3]);
                t2[4] = fmaf(wb, g1_.x, t2[4]); t2[5] = fmaf(wb, g1_.y, t2[5]);
                t2[6] = fmaf(wb, g1_.z, t2[6]); t2[7] = fmaf(wb, g1_.w, t2[7]);
            }
        }
        float qr[8];
#pragma unroll
        for (int c = 0; c < 8; ++c) {
            const float4 w0 = *(const float4*)&wv[c * 8];
            const float4 w1 = *(const float4*)&wv[c * 8 + 4];
            float s = t2[0] * w0.x;
            s = fmaf(t2[1], w0.y, s); s = fmaf(t2[2], w0.z, s);
            s = fmaf(t2[3], w0.w, s); s = fmaf(t2[4], w1.x, s);
            s = fmaf(t2[5], w1.y, s); s = fmaf(t2[6], w1.z, s);
            s = fmaf(t2[7], w1.w, s);
            qr[c] = s;
        }
        FENCE();  // all om/si reads (whole group, same wave) precede overlay writes
        *(float4*)&sh_P[gl][i][r * 8]     = make_float4(pr[0], pr[1], pr[2], pr[3]);
        *(float4*)&sh_P[gl][i][r * 8 + 4] = make_float4(pr[4], pr[5], pr[6], pr[7]);
        *(float4*)&sh_Q[gl][i][r * 8]     = make_float4(qr[0], qr[1], qr[2], qr[3]);
        *(float4*)&sh_Q[gl][i][r * 8 + 4] = make_float4(qr[4], qr[5], qr[6], qr[7]);
        sh_u[gl][i][r] = uu;
        sh_w[gl][i][r] = ww;
        if (r == 0) { sh_sc[gl][i][0] = a_i; sh_sc[gl][i][1] = s_i; }
    }
    __syncthreads();

    // ---- Phase 2: one (i,j) pair per thread ----
    const int i = t >> 4, j = t & 15;
    float res[GP];
#pragma unroll
    for (int gl = 0; gl < GP; ++gl) {
        const float* Pj = &sh_P[gl][j][0];
        const float* Qi = &sh_Q[gl][i][0];
        float u[8];
#pragma unroll
        for (int b = 0; b < 8; ++b) u[b] = sh_u[gl][i][b];
        float tr = 0.f, upu = 0.f;
#pragma unroll
        for (int a = 0; a < 8; ++a) {
            const float4 p0 = *(const float4*)&Pj[a * 8];
            const float4 p1 = *(const float4*)&Pj[a * 8 + 4];
            const float4 q0 = *(const float4*)&Qi[a * 8];
            const float4 q1 = *(const float4*)&Qi[a * 8 + 4];
            tr = fmaf(p0.x, q0.x, tr); tr = fmaf(p0.y, q0.y, tr);
            tr = fmaf(p0.z, q0.z, tr); tr = fmaf(p0.w, q0.w, tr);
            tr = fmaf(p1.x, q1.x, tr); tr = fmaf(p1.y, q1.y, tr);
            tr = fmaf(p1.z, q1.z, tr); tr = fmaf(p1.w, q1.w, tr);
            float s = p0.x * u[0];
            s = fmaf(p0.y, u[1], s); s = fmaf(p0.z, u[2], s);
            s = fmaf(p0.w, u[3], s); s = fmaf(p1.x, u[4], s);
            s = fmaf(p1.y, u[5], s); s = fmaf(p1.z, u[6], s);
            s = fmaf(p1.w, u[7], s);
            upu = fmaf(u[a], s, upu);
        }
        float wu = 0.f;
#pragma unroll
        for (int a = 0; a < 8; ++a) wu = fmaf(sh_w[gl][j][a], u[a], wu);
        float E = 0.5f * (tr + upu - 2.f * wu + sh_sc[gl][i][0] + sh_sc[gl][j][1]);
        res[gl] = (i == j) ? 0.0f : E;
    }
    *reinterpret_cast<float2*>(&out[(i * NN + j) * GG + g0]) =
        make_float2(res[0], res[1]);
}

extern "C" void kernel_launch(void* const* d_in, const int* in_sizes, int n_in,
                              void* d_out, int out_size, void* d_ws, size_t ws_size,
                              hipStream_t stream) {
    const float* omega = (const float*)d_in[0];
    const float* links = (const float*)d_in[1];
    const float* mu    = (const float*)d_in[2];
    const float* sigma = (const float*)d_in[3];
    float* out = (float*)d_out;
    hipLaunchKernelGGL(pairkl_kernel, dim3(NWG), dim3(256), 0, stream,
                       omega, links, mu, sigma, out);
}